// Round 7
// baseline (35.580 us; speedup 1.0000x reference)
//
#include <hip/hip_runtime.h>

// tensors (1024, 256, 16) fp32, WINDOW=5 -> S=252 windows, 120 triu pairs.
// out[b][p][s] fp32, p = np.triu_indices(16,1) order.
// Grid 2048: block = (batch, pair-half). Block 128 threads; thread owns 2
// consecutive windows (rows 2q..2q+5 in regs) -> one float2 store per pair,
// 512B per wave-store. 4096 waves total (= R1's occupancy), no spill.
#define NB 1024
#define NT 256
#define NF 16
#define NS 252
#define NPAIR 120
#define EPS 1e-5f

typedef float vf2 __attribute__((ext_vector_type(2)));

constexpr int IU[NPAIR] = {
  0,0,0,0,0,0,0,0,0,0,0,0,0,0,0,
  1,1,1,1,1,1,1,1,1,1,1,1,1,1,
  2,2,2,2,2,2,2,2,2,2,2,2,2,
  3,3,3,3,3,3,3,3,3,3,3,3,
  4,4,4,4,4,4,4,4,4,4,4,
  5,5,5,5,5,5,5,5,5,5,
  6,6,6,6,6,6,6,6,6,
  7,7,7,7,7,7,7,7,
  8,8,8,8,8,8,8,
  9,9,9,9,9,9,
  10,10,10,10,10,
  11,11,11,11,
  12,12,12,
  13,13,
  14};
constexpr int JU[NPAIR] = {
  1,2,3,4,5,6,7,8,9,10,11,12,13,14,15,
  2,3,4,5,6,7,8,9,10,11,12,13,14,15,
  3,4,5,6,7,8,9,10,11,12,13,14,15,
  4,5,6,7,8,9,10,11,12,13,14,15,
  5,6,7,8,9,10,11,12,13,14,15,
  6,7,8,9,10,11,12,13,14,15,
  7,8,9,10,11,12,13,14,15,
  8,9,10,11,12,13,14,15,
  9,10,11,12,13,14,15,
  10,11,12,13,14,15,
  11,12,13,14,15,
  12,13,14,15,
  13,14,15,
  14,15,
  15};

template<int H>
__device__ __forceinline__ void half_pairs(const float (&x)[6][NF],
                                           const float* A0, const float* A1,
                                           const float* M0, const float* M1,
                                           float* outb, bool active) {
    #pragma unroll
    for (int k = 0; k < 60; ++k) {
        const int p = H * 60 + k;         // compile-time after unroll
        const int i = IU[p], j = JU[p];   // fold to constants -> regs stay regs
        float z0 = x[0][i]*x[0][j], z1 = x[1][i]*x[1][j], z2 = x[2][i]*x[2][j],
              z3 = x[3][i]*x[3][j], z4 = x[4][i]*x[4][j], z5 = x[5][i]*x[5][j];
        float t0 = z0 + z1 + z2 + z3 + z4;
        float t1 = t0 - z0 + z5;
        float c0 = t0 * 0.2f * (A0[i] * A0[j]) - M0[i] * M0[j];
        float c1 = t1 * 0.2f * (A1[i] * A1[j]) - M1[i] * M1[j];
        vf2 c = {c0, c1};
        if (active) *reinterpret_cast<vf2*>(outb + (size_t)p * NS) = c;
    }
}

__global__ __launch_bounds__(128, 2) void ts_corr_kernel(const float* __restrict__ in,
                                                         float* __restrict__ out) {
    const int blk = blockIdx.x;
    const int b = blk >> 1;
    const int h = blk & 1;
    const int tid = threadIdx.x;            // 0..127
    const bool active = tid < (NS / 2);     // 126 s-pairs
    const int q = active ? tid : (NS / 2) - 1;
    const int r0 = q * 2;                   // rows r0..r0+5 -> windows r0, r0+1

    // Load 6 rows x 16 features into registers (24 float4 loads).
    const float* base = in + ((size_t)b * NT + r0) * NF;
    float x[6][NF];
    #pragma unroll
    for (int w = 0; w < 6; ++w) {
        const float4* r4 = reinterpret_cast<const float4*>(base + w * NF);
        #pragma unroll
        for (int c = 0; c < 4; ++c) {
            float4 v = r4[c];
            x[w][c * 4 + 0] = v.x;
            x[w][c * 4 + 1] = v.y;
            x[w][c * 4 + 2] = v.z;
            x[w][c * 4 + 3] = v.w;
        }
    }

    // Per-feature stats for the 2 windows: A = rstd, M = mean*rstd.
    float A0[NF], A1[NF], M0[NF], M1[NF];
    #pragma unroll
    for (int i = 0; i < NF; ++i) {
        float v0 = x[0][i], v1 = x[1][i], v2 = x[2][i],
              v3 = x[3][i], v4 = x[4][i], v5 = x[5][i];
        float s0 = v0 + v1 + v2 + v3 + v4;
        float s1 = s0 - v0 + v5;
        float q0 = v0*v0 + v1*v1 + v2*v2 + v3*v3 + v4*v4;
        float q1 = q0 - v0*v0 + v5*v5;
        float m0 = s0 * 0.2f, m1 = s1 * 0.2f;
        float var0 = (q0 - 5.0f * m0 * m0) * 0.25f;
        float var1 = (q1 - 5.0f * m1 * m1) * 0.25f;
        float rs0 = 1.0f / (sqrtf(fmaxf(var0, 0.0f)) + EPS);
        float rs1 = 1.0f / (sqrtf(fmaxf(var1, 0.0f)) + EPS);
        A0[i] = rs0; A1[i] = rs1;
        M0[i] = m0 * rs0; M1[i] = m1 * rs1;
    }

    float* outb = out + (size_t)b * (NPAIR * NS) + r0;
    if (h == 0) half_pairs<0>(x, A0, A1, M0, M1, outb, active);
    else        half_pairs<1>(x, A0, A1, M0, M1, outb, active);
}

extern "C" void kernel_launch(void* const* d_in, const int* in_sizes, int n_in,
                              void* d_out, int out_size, void* d_ws, size_t ws_size,
                              hipStream_t stream) {
    const float* in = (const float*)d_in[0];
    float* out = (float*)d_out;
    ts_corr_kernel<<<dim3(NB * 2), dim3(128), 0, stream>>>(in, out);
}

// Round 8
// 29.009 us; speedup vs baseline: 1.2265x; 1.2265x over previous
//
#include <hip/hip_runtime.h>

// tensors (1024, 256, 16) fp32, WINDOW=5, STRIDES=1 -> S=252 windows,
// F=16 -> 120 triu pairs. out[b][p][s] fp32, p = triu_indices(16,1) order.
// R1 structure (best measured: 29.1 us): thread = (b, s), scalar coalesced
// stores. Micro-opt: fold rstd/sqrt(5) into window values so each pair is
// 1 init-FMA + 5 FMA + store.
#define NB 1024
#define NT 256
#define NF 16
#define NW 5
#define NS 252   // NT - NW + 1
#define NPAIR 120
#define EPS 1e-5f

__global__ __launch_bounds__(256) void ts_corr_kernel(const float* __restrict__ in,
                                                      float* __restrict__ out) {
    const int b = blockIdx.x;
    const int tid = threadIdx.x;
    const bool active = tid < NS;
    const int s = active ? tid : NS - 1;  // inactive lanes compute a dup, skip writes

    // Load the 5x16 window into registers (vectorized float4 loads).
    const float* row0 = in + ((size_t)b * NT + s) * NF;
    float x[NW][NF];
    #pragma unroll
    for (int w = 0; w < NW; ++w) {
        const float4* r4 = reinterpret_cast<const float4*>(row0 + w * NF);
        #pragma unroll
        for (int q = 0; q < 4; ++q) {
            float4 v = r4[q];
            x[w][q * 4 + 0] = v.x;
            x[w][q * 4 + 1] = v.y;
            x[w][q * 4 + 2] = v.z;
            x[w][q * 4 + 3] = v.w;
        }
    }

    // Per-feature stats; then scale window values in place:
    //   y[w][i] = x[w][i] * rstd[i] / sqrt(5),  M[i] = mean[i] * rstd[i]
    // so corr(i,j) = sum_w y[w][i]*y[w][j] - M[i]*M[j].
    const float RSQRT5 = 0.44721359549995793f;
    float M[NF];
    #pragma unroll
    for (int i = 0; i < NF; ++i) {
        float sum = 0.f, sq = 0.f;
        #pragma unroll
        for (int w = 0; w < NW; ++w) {
            sum += x[w][i];
            sq  += x[w][i] * x[w][i];
        }
        float m = sum * (1.0f / NW);
        float var = (sq - (float)NW * m * m) * (1.0f / (NW - 1));
        var = fmaxf(var, 0.0f);
        float rstd = 1.0f / (sqrtf(var) + EPS);
        M[i] = m * rstd;
        float sc = rstd * RSQRT5;
        #pragma unroll
        for (int w = 0; w < NW; ++w) x[w][i] *= sc;
    }

    // 120 upper-triangle pairs; scalar stores, coalesced across the wave per p.
    float* outb = out + (size_t)b * NPAIR * NS + s;
    int p = 0;
    #pragma unroll
    for (int i = 0; i < NF; ++i) {
        #pragma unroll
        for (int j = i + 1; j < NF; ++j) {
            float acc = -M[i] * M[j];
            #pragma unroll
            for (int w = 0; w < NW; ++w) acc += x[w][i] * x[w][j];
            if (active) outb[(size_t)p * NS] = acc;
            ++p;
        }
    }
}

extern "C" void kernel_launch(void* const* d_in, const int* in_sizes, int n_in,
                              void* d_out, int out_size, void* d_ws, size_t ws_size,
                              hipStream_t stream) {
    const float* in = (const float*)d_in[0];
    float* out = (float*)d_out;
    ts_corr_kernel<<<dim3(NB), dim3(256), 0, stream>>>(in, out);
}